// Round 1
// baseline (568.610 us; speedup 1.0000x reference)
//
#include <hip/hip_runtime.h>
#include <hip/hip_bf16.h>

// ---------------------------------------------------------------------------
// parsingNet: pool(1x1 conv 2048->8) -> GAT1(8->4x16) -> GAT2(64->8)
//             -> fc1(1800->2048,relu) -> fc2(2048->20800)
// B=128, grid graph 9x25 (225 nodes, 8-neighborhood + self loop).
// ---------------------------------------------------------------------------

typedef __attribute__((ext_vector_type(8))) short bh8_t;   // 8 x bf16 (4 VGPR)
typedef __attribute__((ext_vector_type(4))) float f32x4;

static __device__ __forceinline__ short f2bs(float f) {
    __hip_bfloat16 h = __float2bfloat16(f);
    return *reinterpret_cast<short*>(&h);
}
static __device__ __forceinline__ unsigned pack2(short a, short b) {
    return (unsigned)(unsigned short)a | ((unsigned)(unsigned short)b << 16);
}

// ---------------------------------------------------------------------------
// Kernel 1: pool partials.  grid = 128 b * 8 chunks.  out[b][chunk][n][o]
// fea_partial[b,ch,n,o] = sum_{c in chunk} x4[b,c,n] * pool_w[o,c]
// ---------------------------------------------------------------------------
__global__ __launch_bounds__(256) void pool_kernel(const float* __restrict__ x4,
                                                   const float* __restrict__ pool_w,
                                                   float* __restrict__ part) {
    const int b  = blockIdx.x >> 3;
    const int ch = blockIdx.x & 7;
    __shared__ __align__(16) float ws[256 * 8];   // [c_local][o]
    const int tid = threadIdx.x;
    for (int i = tid; i < 2048; i += 256)
        ws[i] = pool_w[(i & 7) * 2048 + ch * 256 + (i >> 3)];
    __syncthreads();
    if (tid < 225) {
        const float* xp = x4 + ((size_t)b * 2048 + (size_t)ch * 256) * 225 + tid;
        float a0 = 0, a1 = 0, a2 = 0, a3 = 0, a4 = 0, a5 = 0, a6 = 0, a7 = 0;
#pragma unroll 8
        for (int c = 0; c < 256; ++c) {
            float v = xp[c * 225];
            const float4 wa = *reinterpret_cast<const float4*>(&ws[c * 8]);
            const float4 wb = *reinterpret_cast<const float4*>(&ws[c * 8 + 4]);
            a0 += v * wa.x; a1 += v * wa.y; a2 += v * wa.z; a3 += v * wa.w;
            a4 += v * wb.x; a5 += v * wb.y; a6 += v * wb.z; a7 += v * wb.w;
        }
        float* dst = part + (size_t)b * 14400 + ch * 1800 + tid * 8;
        dst[0] = a0; dst[1] = a1; dst[2] = a2; dst[3] = a3;
        dst[4] = a4; dst[5] = a5; dst[6] = a6; dst[7] = a7;
    }
}

// ---------------------------------------------------------------------------
// Kernel 2: GAT1.  one block per b.
// fea[225][8] -> h[225][64] -> attention(4 heads, d=16) -> relu(+bias) -> x1
// LDS: fea 7200B + h 57600B = 64800B.  fea region reused for asrc/adst (900+900).
// ---------------------------------------------------------------------------
__global__ __launch_bounds__(256) void gat1_kernel(const float* __restrict__ part,
                                                   const float* __restrict__ pool_b,
                                                   const float* __restrict__ w,
                                                   const float* __restrict__ a_src,
                                                   const float* __restrict__ a_dst,
                                                   const float* __restrict__ bias,
                                                   float* __restrict__ x1) {
    __shared__ __align__(16) float fea[1800];      // then reused: [0..899]=asrc, [900..1799]=adst
    __shared__ __align__(16) float h[14400];       // [n][64]
    const int b = blockIdx.x;
    const int tid = threadIdx.x;

    // phase 1: reduce 8 partials
    for (int i = tid; i < 1800; i += 256) {
        const float* p = part + (size_t)b * 14400 + i;
        float s = 0;
#pragma unroll
        for (int c = 0; c < 8; ++c) s += p[c * 1800];
        fea[i] = s + pool_b[i & 7];
    }
    __syncthreads();

    // phase 2: h = fea @ w  (225x8 @ 8x64)
    {
        const int o = tid & 63, mr = tid >> 6;
        float wv[8];
#pragma unroll
        for (int k = 0; k < 8; ++k) wv[k] = w[k * 64 + o];
        for (int n = mr; n < 225; n += 4) {
            float acc = 0;
#pragma unroll
            for (int k = 0; k < 8; ++k) acc += fea[n * 8 + k] * wv[k];
            h[n * 64 + o] = acc;
        }
    }
    __syncthreads();

    // phase 2.5: asrc/adst per (node, head) into fea region
    for (int t = tid; t < 900; t += 256) {
        const int n = t >> 2, hd = t & 3;
        const float* hp = &h[n * 64 + hd * 16];
        float as = 0, ad = 0;
#pragma unroll
        for (int d = 0; d < 16; ++d) {
            float hv = hp[d];
            as += hv * a_src[hd * 16 + d];
            ad += hv * a_dst[hd * 16 + d];
        }
        fea[t] = as;
        fea[900 + t] = ad;
    }
    __syncthreads();

    // phase 3: attention + relu + bias
    for (int task = tid; task < 900; task += 256) {
        const int n = task >> 2, hd = task & 3;
        const int i = n / 25, j = n % 25;
        const float adn = fea[900 + task];
        float e[9];
        int sid[9];
        float mx = -1e30f;
#pragma unroll
        for (int t9 = 0; t9 < 9; ++t9) {
            const int di = t9 / 3 - 1, dj = t9 % 3 - 1;
            const int ni = i + di, nj = j + dj;
            const bool valid = ((unsigned)ni < 9u) && ((unsigned)nj < 25u);
            const int s = valid ? ni * 25 + nj : n;
            sid[t9] = s;
            float ev = fea[s * 4 + hd] + adn;
            ev = ev >= 0.f ? ev : 0.2f * ev;          // leaky_relu(0.2)
            e[t9] = valid ? ev : -1e30f;
            mx = fmaxf(mx, e[t9]);
        }
        float sum = 0;
#pragma unroll
        for (int t9 = 0; t9 < 9; ++t9) {
            float ex = __expf(e[t9] - mx);            // invalid -> exp(-huge)=0
            e[t9] = ex;
            sum += ex;
        }
        const float inv = 1.f / sum;
        float out[16] = {};
#pragma unroll
        for (int t9 = 0; t9 < 9; ++t9) {
            const float al = e[t9] * inv;
            const float* hp = &h[sid[t9] * 64 + hd * 16];
#pragma unroll
            for (int d = 0; d < 16; ++d) out[d] += al * hp[d];
        }
        float* dst = x1 + (size_t)b * 14400 + n * 64 + hd * 16;
        const float* bp = bias + hd * 16;
#pragma unroll
        for (int d = 0; d < 16; ++d) dst[d] = fmaxf(out[d] + bp[d], 0.f);
    }
}

// ---------------------------------------------------------------------------
// Kernel 3: GAT2 (1 head, d=8, concat=False -> identity mean) -> flat (bf16)
// LDS: xs 57600 + h2 7200 = 64800B
// ---------------------------------------------------------------------------
__global__ __launch_bounds__(256) void gat2_kernel(const float* __restrict__ x1,
                                                   const float* __restrict__ w,
                                                   const float* __restrict__ a_src,
                                                   const float* __restrict__ a_dst,
                                                   const float* __restrict__ bias,
                                                   short* __restrict__ flat) {
    __shared__ __align__(16) float xs[14400];   // [n][64]
    __shared__ __align__(16) float h[1800];     // [n][8]
    const int b = blockIdx.x;
    const int tid = threadIdx.x;
    for (int i = tid; i < 14400; i += 256) xs[i] = x1[(size_t)b * 14400 + i];
    __syncthreads();
    for (int t = tid; t < 1800; t += 256) {
        const int o = t & 7, n = t >> 3;
        float acc = 0;
#pragma unroll 8
        for (int k = 0; k < 64; ++k) acc += xs[n * 64 + k] * w[k * 8 + o];
        h[t] = acc;
    }
    __syncthreads();
    if (tid < 225) {
        const int n = tid, i = n / 25, j = n % 25;
        float av[8], dv[8];
#pragma unroll
        for (int d = 0; d < 8; ++d) { av[d] = a_src[d]; dv[d] = a_dst[d]; }
        float adn = 0;
#pragma unroll
        for (int d = 0; d < 8; ++d) adn += h[n * 8 + d] * dv[d];
        float e[9];
        int sid[9];
        float mx = -1e30f;
#pragma unroll
        for (int t9 = 0; t9 < 9; ++t9) {
            const int di = t9 / 3 - 1, dj = t9 % 3 - 1;
            const int ni = i + di, nj = j + dj;
            const bool valid = ((unsigned)ni < 9u) && ((unsigned)nj < 25u);
            const int s = valid ? ni * 25 + nj : n;
            sid[t9] = s;
            float as = 0;
#pragma unroll
            for (int d = 0; d < 8; ++d) as += h[s * 8 + d] * av[d];
            float ev = as + adn;
            ev = ev >= 0.f ? ev : 0.2f * ev;
            e[t9] = valid ? ev : -1e30f;
            mx = fmaxf(mx, e[t9]);
        }
        float sum = 0;
#pragma unroll
        for (int t9 = 0; t9 < 9; ++t9) {
            float ex = __expf(e[t9] - mx);
            e[t9] = ex;
            sum += ex;
        }
        const float inv = 1.f / sum;
        float out[8] = {};
#pragma unroll
        for (int t9 = 0; t9 < 9; ++t9) {
            const float al = e[t9] * inv;
            const float* hp = &h[sid[t9] * 8];
#pragma unroll
            for (int d = 0; d < 8; ++d) out[d] += al * hp[d];
        }
        short* dst = flat + (size_t)b * 1800 + n * 8;
#pragma unroll
        for (int d = 0; d < 8; ++d) dst[d] = f2bs(out[d] + bias[d]);
    }
}

// ---------------------------------------------------------------------------
// Kernel 4/5: MFMA GEMM  C[128,N] = A_bf16[128,K] @ bf16(Wf[K,N]) (+bias, opt relu)
// BM=128, BK=32, 256 threads (4 waves), 16x16x32 bf16 MFMA.
// W is fp32 in HBM, converted to bf16 inline during LDS staging (no extra pass).
// LDS rows padded to 40 bf16 (80B, 16B-aligned, 2-way-bank-free for b128 frags).
// ---------------------------------------------------------------------------
template <int BN, int MT, int NT, int NWN, bool RELU, bool OUT_BF16>
__global__ __launch_bounds__(256) void gemm_mfma(const short* __restrict__ A,
                                                 const float* __restrict__ Wf,
                                                 const float* __restrict__ bias,
                                                 void* __restrict__ outp,
                                                 int K, int N) {
    constexpr int LDT = 40;
    __shared__ __align__(16) short sA[128 * LDT];
    __shared__ __align__(16) short sB[BN * LDT];   // transposed: [n][k]
    const int tid = threadIdx.x;
    const int lane = tid & 63;
    const int wave = tid >> 6;
    const int n0 = blockIdx.x * BN;
    const int wm0 = (wave / NWN) * (MT * 16);
    const int wn0 = (wave % NWN) * (NT * 16);
    const int lm = lane & 15;
    const int lkb = (lane >> 4) * 8;

    const int am = tid >> 1;          // A row 0..127
    const int akh = tid & 1;          // k half (16 elems)
    constexpr int EPT = (32 * BN) / 256;
    const int bn_ = tid % BN;
    const int bk0 = (tid / BN) * EPT;

    f32x4 acc[MT][NT] = {};

    const int nkt = (K + 31) >> 5;
    for (int kt = 0; kt < nkt; ++kt) {
        const int k0 = kt << 5;
        if (k0 + 32 <= K) {
            // -------- fast path --------
            const uint4* src = reinterpret_cast<const uint4*>(A + (size_t)am * K + k0 + akh * 16);
            uint4 v0 = src[0];
            uint4 v1 = src[1];
            float bv[EPT];
#pragma unroll
            for (int jj = 0; jj < EPT; ++jj)
                bv[jj] = Wf[(size_t)(k0 + bk0 + jj) * N + n0 + bn_];
            uint4* dstA = reinterpret_cast<uint4*>(&sA[am * LDT + akh * 16]);
            dstA[0] = v0;
            dstA[1] = v1;
            unsigned uw[EPT / 2];
#pragma unroll
            for (int jj = 0; jj < EPT / 2; ++jj)
                uw[jj] = pack2(f2bs(bv[2 * jj]), f2bs(bv[2 * jj + 1]));
            if constexpr (EPT == 8) {
                uint4 u;
                u.x = uw[0]; u.y = uw[1]; u.z = uw[2]; u.w = uw[3];
                *reinterpret_cast<uint4*>(&sB[bn_ * LDT + bk0]) = u;
            } else {
                *reinterpret_cast<unsigned*>(&sB[bn_ * LDT + bk0]) = uw[0];
            }
        } else {
            // -------- K-boundary tile (fc1: K=1800), zero-pad --------
#pragma unroll
            for (int jj = 0; jj < 16; ++jj) {
                const int kk = k0 + akh * 16 + jj;
                sA[am * LDT + akh * 16 + jj] = (kk < K) ? A[(size_t)am * K + kk] : (short)0;
            }
#pragma unroll
            for (int jj = 0; jj < EPT; ++jj) {
                const int kk = k0 + bk0 + jj;
                const float v = (kk < K) ? Wf[(size_t)kk * N + n0 + bn_] : 0.f;
                sB[bn_ * LDT + bk0 + jj] = f2bs(v);
            }
        }
        __syncthreads();
        bh8_t bfr[NT];
#pragma unroll
        for (int nt = 0; nt < NT; ++nt)
            bfr[nt] = *reinterpret_cast<const bh8_t*>(&sB[(wn0 + nt * 16 + lm) * LDT + lkb]);
#pragma unroll
        for (int mt = 0; mt < MT; ++mt) {
            bh8_t afr = *reinterpret_cast<const bh8_t*>(&sA[(wm0 + mt * 16 + lm) * LDT + lkb]);
#pragma unroll
            for (int nt = 0; nt < NT; ++nt)
                acc[mt][nt] = __builtin_amdgcn_mfma_f32_16x16x32_bf16(afr, bfr[nt], acc[mt][nt], 0, 0, 0);
        }
        __syncthreads();
    }
    // epilogue: C/D layout col=lane&15, row=(lane>>4)*4+r  [m89 verified]
    const int rg = lane >> 4;
#pragma unroll
    for (int nt = 0; nt < NT; ++nt) {
        const int n = n0 + wn0 + nt * 16 + lm;
        const float bv = bias[n];
#pragma unroll
        for (int mt = 0; mt < MT; ++mt) {
#pragma unroll
            for (int r = 0; r < 4; ++r) {
                const int m = wm0 + mt * 16 + rg * 4 + r;
                float v = acc[mt][nt][r] + bv;
                if (RELU) v = fmaxf(v, 0.f);
                if (OUT_BF16)
                    reinterpret_cast<short*>(outp)[(size_t)m * N + n] = f2bs(v);
                else
                    reinterpret_cast<float*>(outp)[(size_t)m * N + n] = v;
            }
        }
    }
}

// ---------------------------------------------------------------------------
extern "C" void kernel_launch(void* const* d_in, const int* in_sizes, int n_in,
                              void* d_out, int out_size, void* d_ws, size_t ws_size,
                              hipStream_t stream) {
    const float* x4        = (const float*)d_in[0];
    const float* pool_w    = (const float*)d_in[1];
    const float* pool_b    = (const float*)d_in[2];
    const float* gat1_w    = (const float*)d_in[3];
    const float* gat1_asrc = (const float*)d_in[4];
    const float* gat1_adst = (const float*)d_in[5];
    const float* gat1_b    = (const float*)d_in[6];
    const float* gat2_w    = (const float*)d_in[7];
    const float* gat2_asrc = (const float*)d_in[8];
    const float* gat2_adst = (const float*)d_in[9];
    const float* gat2_b    = (const float*)d_in[10];
    const float* w1        = (const float*)d_in[11];
    const float* b1        = (const float*)d_in[12];
    const float* w2        = (const float*)d_in[13];
    const float* b2        = (const float*)d_in[14];
    // d_in[15] edge_index: fixed 9x25 grid, hardcoded in kernels.
    float* out = (float*)d_out;

    char* ws = (char*)d_ws;
    float* part = (float*)ws;                        // 128*8*1800*4  = 7,372,800 B
    float* x1   = (float*)(ws + 7372800);            // 128*225*64*4  = 7,372,800 B
    short* flat = (short*)(ws + 14745600);           // 128*1800*2    =   460,800 B
    short* hid  = (short*)(ws + 15206400);           // 128*2048*2    =   524,288 B

    pool_kernel<<<1024, 256, 0, stream>>>(x4, pool_w, part);
    gat1_kernel<<<128, 256, 0, stream>>>(part, pool_b, gat1_w, gat1_asrc, gat1_adst, gat1_b, x1);
    gat2_kernel<<<128, 256, 0, stream>>>(x1, gat2_w, gat2_asrc, gat2_adst, gat2_b, flat);
    // fc1: K=1800 (zero-padded to 57 k-tiles), N=2048, relu, bf16 out
    gemm_mfma<16, 2, 1, 1, true, true><<<128, 256, 0, stream>>>(flat, w1, b1, (void*)hid, 1800, 2048);
    // fc2: K=2048, N=20800, fp32 out
    gemm_mfma<64, 4, 2, 2, false, false><<<325, 256, 0, stream>>>(hid, w2, b2, (void*)out, 2048, 20800);
}